// Round 11
// baseline (273.224 us; speedup 1.0000x reference)
//
#include <hip/hip_runtime.h>
#include <hip/hip_bf16.h>

#define NIN 1024
#define NL 128
#define MS 16384    // 128x128 matrix slot (elements)
#define CMS 32768   // 256x128 C slot (elements)

typedef __attribute__((ext_vector_type(8))) short bf16x8_t;
typedef __attribute__((ext_vector_type(4))) float f32x4_t;

__device__ inline unsigned short f2bf(float f) {
    __hip_bfloat16 h = __float2bfloat16(f);
    return *reinterpret_cast<unsigned short*>(&h);
}

// f32 tile: D[r0..r0+32)[j0..j0+64) = A_rows @ B(128x128); optional bf16 copy.
__device__ __forceinline__ void pmm32x64(const float* __restrict__ A,
                                         const float* __restrict__ B,
                                         float* __restrict__ D,
                                         unsigned short* __restrict__ Db,
                                         int r0, int j0, char* lds) {
    float* Bl = (float*)lds;                        // [128][64] 32 KB
    float (*At)[36] = (float(*)[36])(lds + 32768);  // [128][36] 18 KB
    int t = threadIdx.x;
    for (int idx = t; idx < 2048; idx += 256) {
        int row = idx >> 4, c = idx & 15;
        *(float4*)&Bl[row * 64 + c * 4] = *(const float4*)&B[row * NL + j0 + c * 4];
    }
    for (int idx = t; idx < 4096; idx += 256) {
        int m = idx >> 7, kk = idx & 127;
        At[kk][m] = A[(size_t)(r0 + m) * NL + kk];
    }
    __syncthreads();
    int j = t & 63, rg = t >> 6;
    float acc[8];
#pragma unroll
    for (int q = 0; q < 8; ++q) acc[q] = 0.f;
#pragma unroll 4
    for (int kk = 0; kk < NL; ++kk) {
        float bv = Bl[kk * 64 + j];
        const f32x4_t* ap = (const f32x4_t*)&At[kk][rg * 8];
        f32x4_t a0 = ap[0], a1 = ap[1];
        acc[0] += a0[0] * bv; acc[1] += a0[1] * bv;
        acc[2] += a0[2] * bv; acc[3] += a0[3] * bv;
        acc[4] += a1[0] * bv; acc[5] += a1[1] * bv;
        acc[6] += a1[2] * bv; acc[7] += a1[3] * bv;
    }
#pragma unroll
    for (int q = 0; q < 8; ++q) {
        size_t off = (size_t)(r0 + rg * 8 + q) * NL + j0 + j;
        D[off] = acc[q];
        if (Db) Db[off] = f2bf(acc[q]);
    }
}

// H tile (bf16 MFMA, swapped operands): H[(n*16+a)][m] = sum_l F[n,l]*T^{a+1}[m,l]
__device__ __forceinline__ void hmfma(const unsigned short* __restrict__ Fb,
                                      const unsigned short* __restrict__ Wa,
                                      unsigned short* __restrict__ H,
                                      int a, int nt, char* lds) {
    char* lB = lds;  // swizzled T tile, 32 KB
    int t = threadIdx.x;
    for (int i = t; i < 2048; i += 256) {
        int row = i >> 4, c = i & 15;
        int sw = (c * 16) ^ ((row & 7) << 4);
        *(bf16x8_t*)(lB + row * 256 + sw) = *(const bf16x8_t*)(Wa + (size_t)row * NL + c * 8);
    }
    __syncthreads();
    int w = t >> 6, lane = t & 63;
    int wn = (w >> 1) * 64, wm = (w & 1) * 64;
    int r = lane & 15, g = lane >> 4;
    const unsigned short* Ag = Fb + (size_t)(nt * 128) * NL;
    bf16x8_t av[4][4];  // [kk][aa]
#pragma unroll
    for (int kk = 0; kk < 4; ++kk) {
        int c16 = kk * 4 + g;
#pragma unroll
        for (int aa = 0; aa < 4; ++aa)
            av[kk][aa] = *(const bf16x8_t*)(Ag + (size_t)(wn + aa * 16 + r) * NL + c16 * 8);
    }
    f32x4_t acc[4][4];
#pragma unroll
    for (int aa = 0; aa < 4; ++aa)
#pragma unroll
        for (int bb = 0; bb < 4; ++bb) acc[aa][bb] = (f32x4_t){0.f, 0.f, 0.f, 0.f};
#pragma unroll
    for (int kk = 0; kk < 4; ++kk) {
        int c16 = kk * 4 + g;
        bf16x8_t bv[4];
#pragma unroll
        for (int bb = 0; bb < 4; ++bb) {
            int rowB = wm + bb * 16 + r;
            bv[bb] = *(const bf16x8_t*)(lB + rowB * 256 + ((c16 * 16) ^ ((rowB & 7) << 4)));
        }
#pragma unroll
        for (int aa = 0; aa < 4; ++aa)
#pragma unroll
            for (int bb = 0; bb < 4; ++bb)
                acc[aa][bb] = __builtin_amdgcn_mfma_f32_16x16x32_bf16(bv[bb], av[kk][aa], acc[aa][bb], 0, 0, 0);
    }
#pragma unroll
    for (int aa = 0; aa < 4; ++aa) {
        int n = nt * 128 + wn + aa * 16 + r;
#pragma unroll
        for (int bb = 0; bb < 4; ++bb) {
            int m0 = wm + bb * 16 + g * 4;
            ushort4 o;
            o.x = f2bf(acc[aa][bb][0]); o.y = f2bf(acc[aa][bb][1]);
            o.z = f2bf(acc[aa][bb][2]); o.w = f2bf(acc[aa][bb][3]);
            *(ushort4*)&H[((size_t)n * 16 + a) * NL + m0] = o;
        }
    }
}

// ---------------- one preamble phase per launch -----------------------------
__global__ __launch_bounds__(256) void k_phase(int ph,
                                               const float* __restrict__ x,
                                               const float* __restrict__ tf,
                                               const float* __restrict__ tr,
                                               float* __restrict__ W,
                                               unsigned short* __restrict__ Wb,
                                               unsigned short* __restrict__ Fb,
                                               float* __restrict__ Cf,
                                               unsigned short* __restrict__ Cc,
                                               unsigned short* __restrict__ H) {
    __shared__ __align__(16) char lds[51200];
    int blk = blockIdx.x, t = threadIdx.x;
    if (ph == 0) {
        if (blk < 128) {
            float* xr = (float*)lds;  // [2][1024]
            int b0 = blk * 2;
            for (int idx = t; idx < 512; idx += 256) {
                int rr = idx >> 8, c = idx & 255;
                ((float4*)xr)[rr * 256 + c] =
                    ((const float4*)(x + (size_t)(b0 + rr) * NIN))[c];
            }
            __syncthreads();
            int rr = t >> 7, col = t & 127;
            const float* xp = xr + rr * NIN;
            float a = 0.f;
#pragma unroll 8
            for (int i = 0; i < NIN; ++i) a += xp[i] * tf[i * NL + col];
            Cf[(size_t)(b0 + rr) * NL + col] = a;
            Cc[(size_t)(b0 + rr) * NL + col] = f2bf(a);
        } else if (blk < 192) {
            int id = (blk - 128) * 256 + t;  // 0..16383
            float v = tr[id];
            W[id] = v;
            Wb[id] = f2bf(v);
            for (int i = id; i < NIN * NL; i += 16384) Fb[i] = f2bf(tf[i]);
        } else {
            int tt = blk - 192;  // 0..7: T^2 = tr @ tr -> slot 1
            pmm32x64(tr, tr, W + MS, Wb + MS,
                     ((tt >> 1) & 3) * 32, (tt & 1) * 64, lds);
        }
    } else if (ph <= 3) {
        int m = 2 << (ph - 1);  // 2,4,8
        int i = blk >> 3, tt = blk & 7;
        pmm32x64(W + (size_t)i * MS, W + (size_t)(m - 1) * MS,
                 W + (size_t)(m + i) * MS, Wb + (size_t)(m + i) * MS,
                 ((tt >> 1) & 3) * 32, (tt & 1) * 64, lds);
    } else {
        int lv = ph - 4;    // 0..3
        int b2s = 15 + lv;  // W slot of T^{16<<lv}
        int ncp = 1 << lv;
        if (lv < 3 && blk < 8) {
            pmm32x64(W + (size_t)b2s * MS, W + (size_t)b2s * MS,
                     W + (size_t)(16 + lv) * MS, nullptr,
                     ((blk >> 1) & 3) * 32, (blk & 1) * 64, lds);
        } else if (blk >= 8 && blk < 8 + ncp * 16) {
            int rel = blk - 8, q = rel >> 4, tt = rel & 15;
            pmm32x64(Cf + (size_t)q * CMS, W + (size_t)b2s * MS,
                     Cf + (size_t)(ncp + q) * CMS, Cc + (size_t)(ncp + q) * CMS,
                     (tt >> 1) * 32, (tt & 1) * 64, lds);
        } else if (lv == 0 && blk >= 24 && blk < 152) {
            int rel = blk - 24;
            hmfma(Fb, Wb + (size_t)(rel >> 3) * MS, H, rel >> 3, rel & 7, lds);
        }
    }
}

// ---------------- k_main: out = Cc_j @ H^T, NT stores ----------------------
__global__ __launch_bounds__(256) void k_main(const unsigned short* __restrict__ Cc,
                                              const unsigned short* __restrict__ H,
                                              float* __restrict__ out) {
    int bid = blockIdx.x;
    int e = ((bid & 7) << 9) | (bid >> 3);
    int ct = e >> 5, j = (e >> 1) & 15, bt = e & 1;
    __shared__ __align__(16) char lB[128 * 256];   // swizzled H tile (32 KB)
    int t = threadIdx.x;
    const unsigned short* Bg = H + (size_t)(ct * 128) * NL;
    for (int i = t; i < 2048; i += 256) {
        int row = i >> 4, c = i & 15;
        int sw = (c * 16) ^ ((row & 7) << 4);
        *(bf16x8_t*)(lB + row * 256 + sw) =
            *(const bf16x8_t*)(Bg + (size_t)row * NL + c * 8);
    }
    __syncthreads();
    int w = t >> 6, lane = t & 63;
    int wr = (w >> 1) * 64;   // wave b-row offset
    int wc = (w & 1) * 64;    // wave col offset
    int r = lane & 15, g = lane >> 4;

    const unsigned short* Arow = Cc + (size_t)j * CMS + (size_t)(bt * 128) * NL;
    bf16x8_t av[4][4];  // [kk][mf]
#pragma unroll
    for (int kk = 0; kk < 4; ++kk) {
        int c16 = kk * 4 + g;
#pragma unroll
        for (int mf = 0; mf < 4; ++mf)
            av[kk][mf] = *(const bf16x8_t*)(Arow + (size_t)(wr + mf * 16 + r) * NL + c16 * 8);
    }
    f32x4_t acc[4][4];  // swapped -> reg dim = col, lane&15 = b-row
#pragma unroll
    for (int mf = 0; mf < 4; ++mf)
#pragma unroll
        for (int nf = 0; nf < 4; ++nf) acc[mf][nf] = (f32x4_t){0.f, 0.f, 0.f, 0.f};
#pragma unroll
    for (int kk = 0; kk < 4; ++kk) {
        int c16 = kk * 4 + g;
        bf16x8_t bv[4];
#pragma unroll
        for (int nf = 0; nf < 4; ++nf) {
            int rowB = wc + nf * 16 + r;
            bv[nf] = *(const bf16x8_t*)(lB + rowB * 256 + ((c16 * 16) ^ ((rowB & 7) << 4)));
        }
#pragma unroll
        for (int mf = 0; mf < 4; ++mf)
#pragma unroll
            for (int nf = 0; nf < 4; ++nf)
                acc[mf][nf] = __builtin_amdgcn_mfma_f32_16x16x32_bf16(bv[nf], av[kk][mf], acc[mf][nf], 0, 0, 0);
    }
#pragma unroll
    for (int mf = 0; mf < 4; ++mf) {
        int brow = bt * 128 + wr + mf * 16 + r;
#pragma unroll
        for (int nf = 0; nf < 4; ++nf) {
            int nn = (w & 1) * 4 + nf;
            __builtin_nontemporal_store(
                acc[mf][nf],
                (f32x4_t*)&out[(size_t)brow * (NIN * 256) +
                               (size_t)(ct * 8 + nn) * 256 + 16 * j + g * 4]);
        }
    }
}

extern "C" void kernel_launch(void* const* d_in, const int* in_sizes, int n_in,
                              void* d_out, int out_size, void* d_ws, size_t ws_size,
                              hipStream_t stream) {
    const float* x = (const float*)d_in[0];
    const float* tf = (const float*)d_in[1];
    const float* tr = (const float*)d_in[2];
    float* out = (float*)d_out;

    // workspace (~9 MB)
    float* W = (float*)d_ws;                              // 20 f32 slots
    float* Cf = W + (size_t)20 * MS;                      // 16 x [256][128] f32
    unsigned short* Wb = (unsigned short*)(Cf + (size_t)16 * CMS);  // 16 bf16 slots
    unsigned short* Fb = Wb + (size_t)16 * MS;            // [1024][128] bf16
    unsigned short* Cc = Fb + (size_t)NIN * NL;           // 16 x [256][128] bf16
    unsigned short* H = Cc + (size_t)16 * CMS;            // [16384][128] bf16 (4 MB)

    static const int grids[8] = {200, 16, 32, 64, 152, 40, 72, 136};
    for (int ph = 0; ph < 8; ++ph) {
        k_phase<<<grids[ph], 256, 0, stream>>>(ph, x, tf, tr, W, Wb, Fb,
                                               Cf, Cc, H);
    }
    // CALIBRATION: k_main twice with identical args (idempotent).
    // dur_R11 - dur_R10 ~= one k_main.
    k_main<<<4096, 256, 0, stream>>>(Cc, H, out);
    k_main<<<4096, 256, 0, stream>>>(Cc, H, out);
}

// Round 12
// 221.600 us; speedup vs baseline: 1.2330x; 1.2330x over previous
//
#include <hip/hip_runtime.h>
#include <hip/hip_bf16.h>

#define NIN 1024
#define NL 128
#define MS 16384    // 128x128 matrix slot (elements)
#define CMS 32768   // 256x128 C slot (elements)
#define FSTRIDE 32  // ints per counter (128 B padding)

typedef __attribute__((ext_vector_type(8))) short bf16x8_t;
typedef __attribute__((ext_vector_type(4))) float f32x4_t;

__device__ inline unsigned short f2bf(float f) {
    __hip_bfloat16 h = __float2bfloat16(f);
    return *reinterpret_cast<unsigned short*>(&h);
}

// ---- flag sync: 8-way sharded counters, agent-scope ------------------------
__device__ __forceinline__ void sigc(int* F, int c) {
    __syncthreads();  // drains this block's stores (vmcnt before barrier)
    if (threadIdx.x == 0)
        __hip_atomic_fetch_add(&F[c * FSTRIDE + (blockIdx.x & 7)], 1,
                               __ATOMIC_RELEASE, __HIP_MEMORY_SCOPE_AGENT);
}
__device__ __forceinline__ void waitc(int* F, int c, int tgt) {
    if (threadIdx.x == 0) {
        for (int it = 0; it < (1 << 22); ++it) {
            int s = 0;
#pragma unroll
            for (int i = 0; i < 8; ++i)
                s += __hip_atomic_load(&F[c * FSTRIDE + i], __ATOMIC_RELAXED,
                                       __HIP_MEMORY_SCOPE_AGENT);
            if (s >= tgt) break;
            __builtin_amdgcn_s_sleep(8);
        }
        __threadfence();  // acquire: invalidate caches before data reads
    }
    __syncthreads();
}

// f32 tile: D[r0..r0+32)[j0..j0+64) = A_rows @ B(128x128); optional bf16 copy.
__device__ __forceinline__ void pmm32x64(const float* __restrict__ A,
                                         const float* __restrict__ B,
                                         float* __restrict__ D,
                                         unsigned short* __restrict__ Db,
                                         int r0, int j0, char* lds) {
    float* Bl = (float*)lds;                        // [128][64] 32 KB
    float (*At)[36] = (float(*)[36])(lds + 32768);  // [128][36] 18 KB
    int t = threadIdx.x;
    for (int idx = t; idx < 2048; idx += 256) {
        int row = idx >> 4, c = idx & 15;
        *(float4*)&Bl[row * 64 + c * 4] = *(const float4*)&B[row * NL + j0 + c * 4];
    }
    for (int idx = t; idx < 4096; idx += 256) {
        int m = idx >> 7, kk = idx & 127;
        At[kk][m] = A[(size_t)(r0 + m) * NL + kk];
    }
    __syncthreads();
    int j = t & 63, rg = t >> 6;
    float acc[8];
#pragma unroll
    for (int q = 0; q < 8; ++q) acc[q] = 0.f;
#pragma unroll 4
    for (int kk = 0; kk < NL; ++kk) {
        float bv = Bl[kk * 64 + j];
        const f32x4_t* ap = (const f32x4_t*)&At[kk][rg * 8];
        f32x4_t a0 = ap[0], a1 = ap[1];
        acc[0] += a0[0] * bv; acc[1] += a0[1] * bv;
        acc[2] += a0[2] * bv; acc[3] += a0[3] * bv;
        acc[4] += a1[0] * bv; acc[5] += a1[1] * bv;
        acc[6] += a1[2] * bv; acc[7] += a1[3] * bv;
    }
#pragma unroll
    for (int q = 0; q < 8; ++q) {
        size_t off = (size_t)(r0 + rg * 8 + q) * NL + j0 + j;
        D[off] = acc[q];
        if (Db) Db[off] = f2bf(acc[q]);
    }
}

// H tile (bf16 MFMA, swapped operands): H[(n*16+a)][m] = sum_l F[n,l]*T^{a+1}[m,l]
__device__ __forceinline__ void hmfma(const unsigned short* __restrict__ Fb,
                                      const unsigned short* __restrict__ Wa,
                                      unsigned short* __restrict__ H,
                                      int a, int nt, char* lds) {
    char* lB = lds;  // swizzled T tile, 32 KB
    int t = threadIdx.x;
    for (int i = t; i < 2048; i += 256) {
        int row = i >> 4, c = i & 15;
        int sw = (c * 16) ^ ((row & 7) << 4);
        *(bf16x8_t*)(lB + row * 256 + sw) = *(const bf16x8_t*)(Wa + (size_t)row * NL + c * 8);
    }
    __syncthreads();
    int w = t >> 6, lane = t & 63;
    int wn = (w >> 1) * 64, wm = (w & 1) * 64;
    int r = lane & 15, g = lane >> 4;
    const unsigned short* Ag = Fb + (size_t)(nt * 128) * NL;
    bf16x8_t av[4][4];  // [kk][aa]
#pragma unroll
    for (int kk = 0; kk < 4; ++kk) {
        int c16 = kk * 4 + g;
#pragma unroll
        for (int aa = 0; aa < 4; ++aa)
            av[kk][aa] = *(const bf16x8_t*)(Ag + (size_t)(wn + aa * 16 + r) * NL + c16 * 8);
    }
    f32x4_t acc[4][4];
#pragma unroll
    for (int aa = 0; aa < 4; ++aa)
#pragma unroll
        for (int bb = 0; bb < 4; ++bb) acc[aa][bb] = (f32x4_t){0.f, 0.f, 0.f, 0.f};
#pragma unroll
    for (int kk = 0; kk < 4; ++kk) {
        int c16 = kk * 4 + g;
        bf16x8_t bv[4];
#pragma unroll
        for (int bb = 0; bb < 4; ++bb) {
            int rowB = wm + bb * 16 + r;
            bv[bb] = *(const bf16x8_t*)(lB + rowB * 256 + ((c16 * 16) ^ ((rowB & 7) << 4)));
        }
#pragma unroll
        for (int aa = 0; aa < 4; ++aa)
#pragma unroll
            for (int bb = 0; bb < 4; ++bb)
                acc[aa][bb] = __builtin_amdgcn_mfma_f32_16x16x32_bf16(bv[bb], av[kk][aa], acc[aa][bb], 0, 0, 0);
    }
#pragma unroll
    for (int aa = 0; aa < 4; ++aa) {
        int n = nt * 128 + wn + aa * 16 + r;
#pragma unroll
        for (int bb = 0; bb < 4; ++bb) {
            int m0 = wm + bb * 16 + g * 4;
            ushort4 o;
            o.x = f2bf(acc[aa][bb][0]); o.y = f2bf(acc[aa][bb][1]);
            o.z = f2bf(acc[aa][bb][2]); o.w = f2bf(acc[aa][bb][3]);
            *(ushort4*)&H[((size_t)n * 16 + a) * NL + m0] = o;
        }
    }
}

// ---------------- fused preamble: flag-synced DAG, one launch ----------------
// counters: 0=W/T2 copies(72) 1=lat0(128) 2=T4(16) 3=T8(32) 4=T16(64)
//           5=T32+C1(24) 6=T64+C23(40) 7=T128+C47(72)
__global__ __launch_bounds__(256) void k_pre(const float* __restrict__ x,
                                             const float* __restrict__ tf,
                                             const float* __restrict__ tr,
                                             float* __restrict__ W,
                                             unsigned short* __restrict__ Wb,
                                             unsigned short* __restrict__ Fb,
                                             float* __restrict__ Cf,
                                             unsigned short* __restrict__ Cc,
                                             unsigned short* __restrict__ H,
                                             int* __restrict__ F) {
    __shared__ __align__(16) char lds[51200];
    int blk = blockIdx.x, t = threadIdx.x;

    // ---- ph0 (no deps)
    if (blk < 128) {
        float* xr = (float*)lds;  // [2][1024]
        int b0 = blk * 2;
        for (int idx = t; idx < 512; idx += 256) {
            int rr = idx >> 8, c = idx & 255;
            ((float4*)xr)[rr * 256 + c] =
                ((const float4*)(x + (size_t)(b0 + rr) * NIN))[c];
        }
        __syncthreads();
        int rr = t >> 7, col = t & 127;
        const float* xp = xr + rr * NIN;
        float a = 0.f;
#pragma unroll 8
        for (int i = 0; i < NIN; ++i) a += xp[i] * tf[i * NL + col];
        Cf[(size_t)(b0 + rr) * NL + col] = a;
        Cc[(size_t)(b0 + rr) * NL + col] = f2bf(a);
        sigc(F, 1);
    } else if (blk < 192) {
        int id = (blk - 128) * 256 + t;  // 0..16383
        float v = tr[id];
        W[id] = v;
        Wb[id] = f2bf(v);
        for (int i = id; i < NIN * NL; i += 16384) Fb[i] = f2bf(tf[i]);
        sigc(F, 0);
    } else if (blk < 200) {
        int tt = blk - 192;  // T^2 = tr@tr -> slot 1
        pmm32x64(tr, tr, W + MS, Wb + MS, ((tt >> 1) & 3) * 32, (tt & 1) * 64, lds);
        sigc(F, 0);
    }

    // ---- T-chain to T^16
    if (blk < 16) {  // T^{3,4} = T^{1,2} @ T^2
        waitc(F, 0, 72);
        int i = blk >> 3, tt = blk & 7;
        pmm32x64(W + (size_t)i * MS, W + MS, W + (size_t)(2 + i) * MS,
                 Wb + (size_t)(2 + i) * MS, ((tt >> 1) & 3) * 32, (tt & 1) * 64, lds);
        sigc(F, 2);
    }
    if (blk < 32) {  // T^{5..8}
        waitc(F, 2, 16);
        int i = blk >> 3, tt = blk & 7;
        pmm32x64(W + (size_t)i * MS, W + 3 * (size_t)MS, W + (size_t)(4 + i) * MS,
                 Wb + (size_t)(4 + i) * MS, ((tt >> 1) & 3) * 32, (tt & 1) * 64, lds);
        sigc(F, 3);
    }
    if (blk < 64) {  // T^{9..16}
        waitc(F, 3, 32);
        int i = blk >> 3, tt = blk & 7;
        pmm32x64(W + (size_t)i * MS, W + 7 * (size_t)MS, W + (size_t)(8 + i) * MS,
                 Wb + (size_t)(8 + i) * MS, ((tt >> 1) & 3) * 32, (tt & 1) * 64, lds);
        sigc(F, 4);
    }

    // ---- after T^16: H (blocks 128..255) runs concurrent with C-chain
    if (blk >= 128) {
        waitc(F, 4, 64);
        int rel = blk - 128;
        hmfma(Fb, Wb + (size_t)(rel >> 3) * MS, H, rel >> 3, rel & 7, lds);
        return;
    }
    if (blk < 8) {  // T^32 = sq(T^16) -> slot 16
        waitc(F, 4, 64);
        pmm32x64(W + 15 * (size_t)MS, W + 15 * (size_t)MS, W + 16 * (size_t)MS,
                 nullptr, ((blk >> 1) & 3) * 32, (blk & 1) * 64, lds);
        sigc(F, 5);
    } else if (blk < 24) {  // C1 = C0 @ T^16
        waitc(F, 4, 64);
        waitc(F, 1, 128);
        int tt = blk - 8;
        pmm32x64(Cf, W + 15 * (size_t)MS, Cf + CMS, Cc + CMS,
                 (tt >> 1) * 32, (tt & 1) * 64, lds);
        sigc(F, 5);
    }
    if (blk < 40) {  // T^64 | C2,3 = C0,1 @ T^32
        waitc(F, 5, 24);
        if (blk < 8)
            pmm32x64(W + 16 * (size_t)MS, W + 16 * (size_t)MS, W + 17 * (size_t)MS,
                     nullptr, ((blk >> 1) & 3) * 32, (blk & 1) * 64, lds);
        else {
            int rel = blk - 8, q = rel >> 4, tt = rel & 15;
            pmm32x64(Cf + (size_t)q * CMS, W + 16 * (size_t)MS,
                     Cf + (size_t)(2 + q) * CMS, Cc + (size_t)(2 + q) * CMS,
                     (tt >> 1) * 32, (tt & 1) * 64, lds);
        }
        sigc(F, 6);
    }
    if (blk < 72) {  // T^128 | C4..7 = C0..3 @ T^64
        waitc(F, 6, 40);
        if (blk < 8)
            pmm32x64(W + 17 * (size_t)MS, W + 17 * (size_t)MS, W + 18 * (size_t)MS,
                     nullptr, ((blk >> 1) & 3) * 32, (blk & 1) * 64, lds);
        else {
            int rel = blk - 8, q = rel >> 4, tt = rel & 15;
            pmm32x64(Cf + (size_t)q * CMS, W + 17 * (size_t)MS,
                     Cf + (size_t)(4 + q) * CMS, Cc + (size_t)(4 + q) * CMS,
                     (tt >> 1) * 32, (tt & 1) * 64, lds);
        }
        sigc(F, 7);
    }
    if (blk < 128) {  // C8..15 = C0..7 @ T^128
        waitc(F, 7, 72);
        int q = blk >> 4, tt = blk & 15;
        pmm32x64(Cf + (size_t)q * CMS, W + 18 * (size_t)MS,
                 Cf + (size_t)(8 + q) * CMS, Cc + (size_t)(8 + q) * CMS,
                 (tt >> 1) * 32, (tt & 1) * 64, lds);
    }
}

// ---------------- k_main: out = Cc_j @ H^T, NT stores ----------------------
__global__ __launch_bounds__(256) void k_main(const unsigned short* __restrict__ Cc,
                                              const unsigned short* __restrict__ H,
                                              float* __restrict__ out) {
    int bid = blockIdx.x;
    int e = ((bid & 7) << 9) | (bid >> 3);
    int ct = e >> 5, j = (e >> 1) & 15, bt = e & 1;
    __shared__ __align__(16) char lB[128 * 256];   // swizzled H tile (32 KB)
    int t = threadIdx.x;
    const unsigned short* Bg = H + (size_t)(ct * 128) * NL;
    for (int i = t; i < 2048; i += 256) {
        int row = i >> 4, c = i & 15;
        int sw = (c * 16) ^ ((row & 7) << 4);
        *(bf16x8_t*)(lB + row * 256 + sw) =
            *(const bf16x8_t*)(Bg + (size_t)row * NL + c * 8);
    }
    __syncthreads();
    int w = t >> 6, lane = t & 63;
    int wr = (w >> 1) * 64;   // wave b-row offset
    int wc = (w & 1) * 64;    // wave col offset
    int r = lane & 15, g = lane >> 4;

    const unsigned short* Arow = Cc + (size_t)j * CMS + (size_t)(bt * 128) * NL;
    bf16x8_t av[4][4];  // [kk][mf]
#pragma unroll
    for (int kk = 0; kk < 4; ++kk) {
        int c16 = kk * 4 + g;
#pragma unroll
        for (int mf = 0; mf < 4; ++mf)
            av[kk][mf] = *(const bf16x8_t*)(Arow + (size_t)(wr + mf * 16 + r) * NL + c16 * 8);
    }
    f32x4_t acc[4][4];  // swapped -> reg dim = col, lane&15 = b-row
#pragma unroll
    for (int mf = 0; mf < 4; ++mf)
#pragma unroll
        for (int nf = 0; nf < 4; ++nf) acc[mf][nf] = (f32x4_t){0.f, 0.f, 0.f, 0.f};
#pragma unroll
    for (int kk = 0; kk < 4; ++kk) {
        int c16 = kk * 4 + g;
        bf16x8_t bv[4];
#pragma unroll
        for (int nf = 0; nf < 4; ++nf) {
            int rowB = wc + nf * 16 + r;
            bv[nf] = *(const bf16x8_t*)(lB + rowB * 256 + ((c16 * 16) ^ ((rowB & 7) << 4)));
        }
#pragma unroll
        for (int mf = 0; mf < 4; ++mf)
#pragma unroll
            for (int nf = 0; nf < 4; ++nf)
                acc[mf][nf] = __builtin_amdgcn_mfma_f32_16x16x32_bf16(bv[nf], av[kk][mf], acc[mf][nf], 0, 0, 0);
    }
#pragma unroll
    for (int mf = 0; mf < 4; ++mf) {
        int brow = bt * 128 + wr + mf * 16 + r;
#pragma unroll
        for (int nf = 0; nf < 4; ++nf) {
            int nn = (w & 1) * 4 + nf;
            __builtin_nontemporal_store(
                acc[mf][nf],
                (f32x4_t*)&out[(size_t)brow * (NIN * 256) +
                               (size_t)(ct * 8 + nn) * 256 + 16 * j + g * 4]);
        }
    }
}

extern "C" void kernel_launch(void* const* d_in, const int* in_sizes, int n_in,
                              void* d_out, int out_size, void* d_ws, size_t ws_size,
                              hipStream_t stream) {
    const float* x = (const float*)d_in[0];
    const float* tf = (const float*)d_in[1];
    const float* tr = (const float*)d_in[2];
    float* out = (float*)d_out;

    // workspace (~9.1 MB)
    float* W = (float*)d_ws;                              // 20 f32 slots
    float* Cf = W + (size_t)20 * MS;                      // 16 x [256][128] f32
    unsigned short* Wb = (unsigned short*)(Cf + (size_t)16 * CMS);  // 16 bf16 slots
    unsigned short* Fb = Wb + (size_t)16 * MS;            // [1024][128] bf16
    unsigned short* Cc = Fb + (size_t)NIN * NL;           // 16 x [256][128] bf16
    unsigned short* H = Cc + (size_t)16 * CMS;            // [16384][128] bf16 (4 MB)
    int* flags = (int*)(H + (size_t)16384 * NL);          // 8 counters x 32 ints

    hipMemsetAsync(flags, 0, 8 * FSTRIDE * sizeof(int), stream);
    k_pre<<<256, 256, 0, stream>>>(x, tf, tr, W, Wb, Fb, Cf, Cc, H, flags);
    k_main<<<4096, 256, 0, stream>>>(Cc, H, out);
}

// Round 13
// 179.910 us; speedup vs baseline: 1.5187x; 1.2317x over previous
//
#include <hip/hip_runtime.h>
#include <hip/hip_bf16.h>

#define NIN 1024
#define NL 128
#define MS 16384    // 128x128 matrix slot (elements)
#define CMS 32768   // 256x128 C slot (elements)

typedef __attribute__((ext_vector_type(8))) short bf16x8_t;
typedef __attribute__((ext_vector_type(4))) float f32x4_t;

__device__ inline unsigned short f2bf(float f) {
    __hip_bfloat16 h = __float2bfloat16(f);
    return *reinterpret_cast<unsigned short*>(&h);
}

// f32 tile: D[r0..r0+32)[j0..j0+64) = A_rows @ B(128x128); optional bf16 copy.
__device__ __forceinline__ void pmm32x64(const float* __restrict__ A,
                                         const float* __restrict__ B,
                                         float* __restrict__ D,
                                         unsigned short* __restrict__ Db,
                                         int r0, int j0, char* lds) {
    float* Bl = (float*)lds;                        // [128][64] 32 KB
    float (*At)[36] = (float(*)[36])(lds + 32768);  // [128][36] 18 KB
    int t = threadIdx.x;
    for (int idx = t; idx < 2048; idx += 256) {
        int row = idx >> 4, c = idx & 15;
        *(float4*)&Bl[row * 64 + c * 4] = *(const float4*)&B[row * NL + j0 + c * 4];
    }
    for (int idx = t; idx < 4096; idx += 256) {
        int m = idx >> 7, kk = idx & 127;
        At[kk][m] = A[(size_t)(r0 + m) * NL + kk];
    }
    __syncthreads();
    int j = t & 63, rg = t >> 6;
    float acc[8];
#pragma unroll
    for (int q = 0; q < 8; ++q) acc[q] = 0.f;
#pragma unroll 4
    for (int kk = 0; kk < NL; ++kk) {
        float bv = Bl[kk * 64 + j];
        const f32x4_t* ap = (const f32x4_t*)&At[kk][rg * 8];
        f32x4_t a0 = ap[0], a1 = ap[1];
        acc[0] += a0[0] * bv; acc[1] += a0[1] * bv;
        acc[2] += a0[2] * bv; acc[3] += a0[3] * bv;
        acc[4] += a1[0] * bv; acc[5] += a1[1] * bv;
        acc[6] += a1[2] * bv; acc[7] += a1[3] * bv;
    }
#pragma unroll
    for (int q = 0; q < 8; ++q) {
        size_t off = (size_t)(r0 + rg * 8 + q) * NL + j0 + j;
        D[off] = acc[q];
        if (Db) Db[off] = f2bf(acc[q]);
    }
}

// H tile (bf16 MFMA, swapped operands): H[(n*16+a)][m] = sum_l F[n,l]*T^{a+1}[m,l]
__device__ __forceinline__ void hmfma(const unsigned short* __restrict__ Fb,
                                      const unsigned short* __restrict__ Wa,
                                      unsigned short* __restrict__ H,
                                      int a, int nt, char* lds) {
    char* lB = lds;  // swizzled T tile, 32 KB
    int t = threadIdx.x;
    for (int i = t; i < 2048; i += 256) {
        int row = i >> 4, c = i & 15;
        int sw = (c * 16) ^ ((row & 7) << 4);
        *(bf16x8_t*)(lB + row * 256 + sw) = *(const bf16x8_t*)(Wa + (size_t)row * NL + c * 8);
    }
    __syncthreads();
    int w = t >> 6, lane = t & 63;
    int wn = (w >> 1) * 64, wm = (w & 1) * 64;
    int r = lane & 15, g = lane >> 4;
    const unsigned short* Ag = Fb + (size_t)(nt * 128) * NL;
    bf16x8_t av[4][4];  // [kk][aa]
#pragma unroll
    for (int kk = 0; kk < 4; ++kk) {
        int c16 = kk * 4 + g;
#pragma unroll
        for (int aa = 0; aa < 4; ++aa)
            av[kk][aa] = *(const bf16x8_t*)(Ag + (size_t)(wn + aa * 16 + r) * NL + c16 * 8);
    }
    f32x4_t acc[4][4];
#pragma unroll
    for (int aa = 0; aa < 4; ++aa)
#pragma unroll
        for (int bb = 0; bb < 4; ++bb) acc[aa][bb] = (f32x4_t){0.f, 0.f, 0.f, 0.f};
#pragma unroll
    for (int kk = 0; kk < 4; ++kk) {
        int c16 = kk * 4 + g;
        bf16x8_t bv[4];
#pragma unroll
        for (int bb = 0; bb < 4; ++bb) {
            int rowB = wm + bb * 16 + r;
            bv[bb] = *(const bf16x8_t*)(lB + rowB * 256 + ((c16 * 16) ^ ((rowB & 7) << 4)));
        }
#pragma unroll
        for (int aa = 0; aa < 4; ++aa)
#pragma unroll
            for (int bb = 0; bb < 4; ++bb)
                acc[aa][bb] = __builtin_amdgcn_mfma_f32_16x16x32_bf16(bv[bb], av[kk][aa], acc[aa][bb], 0, 0, 0);
    }
#pragma unroll
    for (int aa = 0; aa < 4; ++aa) {
        int n = nt * 128 + wn + aa * 16 + r;
#pragma unroll
        for (int bb = 0; bb < 4; ++bb) {
            int m0 = wm + bb * 16 + g * 4;
            ushort4 o;
            o.x = f2bf(acc[aa][bb][0]); o.y = f2bf(acc[aa][bb][1]);
            o.z = f2bf(acc[aa][bb][2]); o.w = f2bf(acc[aa][bb][3]);
            *(ushort4*)&H[((size_t)n * 16 + a) * NL + m0] = o;
        }
    }
}

// ---------------- one preamble phase per launch (R10 structure) -------------
__global__ __launch_bounds__(256) void k_phase(int ph,
                                               const float* __restrict__ x,
                                               const float* __restrict__ tf,
                                               const float* __restrict__ tr,
                                               float* __restrict__ W,
                                               unsigned short* __restrict__ Wb,
                                               unsigned short* __restrict__ Fb,
                                               float* __restrict__ Cf,
                                               unsigned short* __restrict__ Cc,
                                               unsigned short* __restrict__ H) {
    __shared__ __align__(16) char lds[51200];
    int blk = blockIdx.x, t = threadIdx.x;
    if (ph == 0) {
        if (blk < 128) {
            float* xr = (float*)lds;  // [2][1024]
            int b0 = blk * 2;
            for (int idx = t; idx < 512; idx += 256) {
                int rr = idx >> 8, c = idx & 255;
                ((float4*)xr)[rr * 256 + c] =
                    ((const float4*)(x + (size_t)(b0 + rr) * NIN))[c];
            }
            __syncthreads();
            int rr = t >> 7, col = t & 127;
            const float* xp = xr + rr * NIN;
            float a = 0.f;
#pragma unroll 8
            for (int i = 0; i < NIN; ++i) a += xp[i] * tf[i * NL + col];
            Cf[(size_t)(b0 + rr) * NL + col] = a;
            Cc[(size_t)(b0 + rr) * NL + col] = f2bf(a);
        } else if (blk < 192) {
            int id = (blk - 128) * 256 + t;  // 0..16383
            float v = tr[id];
            W[id] = v;
            Wb[id] = f2bf(v);
            for (int i = id; i < NIN * NL; i += 16384) Fb[i] = f2bf(tf[i]);
        } else {
            int tt = blk - 192;  // T^2 = tr @ tr -> slot 1
            pmm32x64(tr, tr, W + MS, Wb + MS,
                     ((tt >> 1) & 3) * 32, (tt & 1) * 64, lds);
        }
    } else if (ph <= 3) {
        int m = 2 << (ph - 1);  // 2,4,8
        int i = blk >> 3, tt = blk & 7;
        pmm32x64(W + (size_t)i * MS, W + (size_t)(m - 1) * MS,
                 W + (size_t)(m + i) * MS, Wb + (size_t)(m + i) * MS,
                 ((tt >> 1) & 3) * 32, (tt & 1) * 64, lds);
    } else {
        int lv = ph - 4;    // 0..3
        int b2s = 15 + lv;  // W slot of T^{16<<lv}
        int ncp = 1 << lv;
        if (lv < 3 && blk < 8) {
            pmm32x64(W + (size_t)b2s * MS, W + (size_t)b2s * MS,
                     W + (size_t)(16 + lv) * MS, nullptr,
                     ((blk >> 1) & 3) * 32, (blk & 1) * 64, lds);
        } else if (blk >= 8 && blk < 8 + ncp * 16) {
            int rel = blk - 8, q = rel >> 4, tt = rel & 15;
            pmm32x64(Cf + (size_t)q * CMS, W + (size_t)b2s * MS,
                     Cf + (size_t)(ncp + q) * CMS, Cc + (size_t)(ncp + q) * CMS,
                     (tt >> 1) * 32, (tt & 1) * 64, lds);
        } else if (lv == 0 && blk >= 24 && blk < 152) {
            int rel = blk - 24;
            hmfma(Fb, Wb + (size_t)(rel >> 3) * MS, H, rel >> 3, rel & 7, lds);
        }
    }
}

// ---------------- k_main: out = Cc_j @ H^T, j-LOOPED, NT stores -------------
// grid 512: block = (ct, bt, jh); stages H-tile once, loops 8 j values so
// each 1KB output row-segment is written entirely by one block (write-combine
// can assemble full DRAM lines despite NT). XCD-chunked: bid%8 -> 16 contig ct.
__global__ __launch_bounds__(256, 2) void k_main(const unsigned short* __restrict__ Cc,
                                                 const unsigned short* __restrict__ H,
                                                 float* __restrict__ out) {
    int bid = blockIdx.x;
    int e = ((bid & 7) << 6) | (bid >> 3);  // 0..511, XCD gets contiguous span
    int ct = e >> 2, bt = (e >> 1) & 1, jh = e & 1;
    __shared__ __align__(16) char lB[128 * 256];   // swizzled H tile (32 KB)
    int t = threadIdx.x;
    const unsigned short* Bg = H + (size_t)(ct * 128) * NL;
    for (int i = t; i < 2048; i += 256) {
        int row = i >> 4, c = i & 15;
        int sw = (c * 16) ^ ((row & 7) << 4);
        *(bf16x8_t*)(lB + row * 256 + sw) =
            *(const bf16x8_t*)(Bg + (size_t)row * NL + c * 8);
    }
    __syncthreads();
    int w = t >> 6, lane = t & 63;
    int wr = (w >> 1) * 64;   // wave b-row offset
    int wc = (w & 1) * 64;    // wave col offset
    int r = lane & 15, g = lane >> 4;

    // preload bv once (H tile is the same for all j)
    bf16x8_t bv[4][4];  // [kk][nf]
#pragma unroll
    for (int kk = 0; kk < 4; ++kk) {
        int c16 = kk * 4 + g;
#pragma unroll
        for (int nf = 0; nf < 4; ++nf) {
            int rowB = wc + nf * 16 + r;
            bv[kk][nf] = *(const bf16x8_t*)(lB + rowB * 256 + ((c16 * 16) ^ ((rowB & 7) << 4)));
        }
    }

    for (int jj = 0; jj < 8; ++jj) {
        int j = jh * 8 + jj;
        const unsigned short* Arow = Cc + (size_t)j * CMS + (size_t)(bt * 128) * NL;
        bf16x8_t av[4][4];  // [kk][mf]
#pragma unroll
        for (int kk = 0; kk < 4; ++kk) {
            int c16 = kk * 4 + g;
#pragma unroll
            for (int mf = 0; mf < 4; ++mf)
                av[kk][mf] = *(const bf16x8_t*)(Arow + (size_t)(wr + mf * 16 + r) * NL + c16 * 8);
        }
        f32x4_t acc[4][4];  // swapped -> reg dim = s-fine, lane&15 = b-row
#pragma unroll
        for (int mf = 0; mf < 4; ++mf)
#pragma unroll
            for (int nf = 0; nf < 4; ++nf) acc[mf][nf] = (f32x4_t){0.f, 0.f, 0.f, 0.f};
#pragma unroll
        for (int kk = 0; kk < 4; ++kk)
#pragma unroll
            for (int mf = 0; mf < 4; ++mf)
#pragma unroll
                for (int nf = 0; nf < 4; ++nf)
                    acc[mf][nf] = __builtin_amdgcn_mfma_f32_16x16x32_bf16(bv[kk][nf], av[kk][mf], acc[mf][nf], 0, 0, 0);
#pragma unroll
        for (int mf = 0; mf < 4; ++mf) {
            int brow = bt * 128 + wr + mf * 16 + r;
#pragma unroll
            for (int nf = 0; nf < 4; ++nf) {
                int nn = (w & 1) * 4 + nf;
                __builtin_nontemporal_store(
                    acc[mf][nf],
                    (f32x4_t*)&out[(size_t)brow * (NIN * 256) +
                                   (size_t)(ct * 8 + nn) * 256 + 16 * j + g * 4]);
            }
        }
    }
}

extern "C" void kernel_launch(void* const* d_in, const int* in_sizes, int n_in,
                              void* d_out, int out_size, void* d_ws, size_t ws_size,
                              hipStream_t stream) {
    const float* x = (const float*)d_in[0];
    const float* tf = (const float*)d_in[1];
    const float* tr = (const float*)d_in[2];
    float* out = (float*)d_out;

    // workspace (~9 MB)
    float* W = (float*)d_ws;                              // 20 f32 slots
    float* Cf = W + (size_t)20 * MS;                      // 16 x [256][128] f32
    unsigned short* Wb = (unsigned short*)(Cf + (size_t)16 * CMS);  // 16 bf16 slots
    unsigned short* Fb = Wb + (size_t)16 * MS;            // [1024][128] bf16
    unsigned short* Cc = Fb + (size_t)NIN * NL;           // 16 x [256][128] bf16
    unsigned short* H = Cc + (size_t)16 * CMS;            // [16384][128] bf16 (4 MB)

    static const int grids[8] = {200, 16, 32, 64, 152, 40, 72, 136};
    for (int ph = 0; ph < 8; ++ph) {
        k_phase<<<grids[ph], 256, 0, stream>>>(ph, x, tf, tr, W, Wb, Fb,
                                               Cf, Cc, H);
    }
    k_main<<<512, 256, 0, stream>>>(Cc, H, out);
}

// Round 14
// 158.404 us; speedup vs baseline: 1.7249x; 1.1358x over previous
//
#include <hip/hip_runtime.h>
#include <hip/hip_bf16.h>

#define NIN 1024
#define NL 128
#define MS 16384    // 128x128 matrix slot (elements)
#define CMS 32768   // 256x128 C slot (elements)

typedef __attribute__((ext_vector_type(8))) short bf16x8_t;
typedef __attribute__((ext_vector_type(4))) float f32x4_t;

__device__ inline unsigned short f2bf(float f) {
    __hip_bfloat16 h = __float2bfloat16(f);
    return *reinterpret_cast<unsigned short*>(&h);
}

// f32 tile: D[r0..r0+32)[j0..j0+64) = A_rows @ B(128x128); optional bf16 copy.
__device__ __forceinline__ void pmm32x64(const float* __restrict__ A,
                                         const float* __restrict__ B,
                                         float* __restrict__ D,
                                         unsigned short* __restrict__ Db,
                                         int r0, int j0, char* lds) {
    float* Bl = (float*)lds;                        // [128][64] 32 KB
    float (*At)[36] = (float(*)[36])(lds + 32768);  // [128][36] 18 KB
    int t = threadIdx.x;
    for (int idx = t; idx < 2048; idx += 256) {
        int row = idx >> 4, c = idx & 15;
        *(float4*)&Bl[row * 64 + c * 4] = *(const float4*)&B[row * NL + j0 + c * 4];
    }
    for (int idx = t; idx < 4096; idx += 256) {
        int m = idx >> 7, kk = idx & 127;
        At[kk][m] = A[(size_t)(r0 + m) * NL + kk];
    }
    __syncthreads();
    int j = t & 63, rg = t >> 6;
    float acc[8];
#pragma unroll
    for (int q = 0; q < 8; ++q) acc[q] = 0.f;
#pragma unroll 4
    for (int kk = 0; kk < NL; ++kk) {
        float bv = Bl[kk * 64 + j];
        const f32x4_t* ap = (const f32x4_t*)&At[kk][rg * 8];
        f32x4_t a0 = ap[0], a1 = ap[1];
        acc[0] += a0[0] * bv; acc[1] += a0[1] * bv;
        acc[2] += a0[2] * bv; acc[3] += a0[3] * bv;
        acc[4] += a1[0] * bv; acc[5] += a1[1] * bv;
        acc[6] += a1[2] * bv; acc[7] += a1[3] * bv;
    }
#pragma unroll
    for (int q = 0; q < 8; ++q) {
        size_t off = (size_t)(r0 + rg * 8 + q) * NL + j0 + j;
        D[off] = acc[q];
        if (Db) Db[off] = f2bf(acc[q]);
    }
}

// H tile (bf16 MFMA, swapped operands): H[(n*16+a)][m] = sum_l F[n,l]*T^{a+1}[m,l]
__device__ __forceinline__ void hmfma(const unsigned short* __restrict__ Fb,
                                      const unsigned short* __restrict__ Wa,
                                      unsigned short* __restrict__ H,
                                      int a, int nt, char* lds) {
    char* lB = lds;  // swizzled T tile, 32 KB
    int t = threadIdx.x;
    for (int i = t; i < 2048; i += 256) {
        int row = i >> 4, c = i & 15;
        int sw = (c * 16) ^ ((row & 7) << 4);
        *(bf16x8_t*)(lB + row * 256 + sw) = *(const bf16x8_t*)(Wa + (size_t)row * NL + c * 8);
    }
    __syncthreads();
    int w = t >> 6, lane = t & 63;
    int wn = (w >> 1) * 64, wm = (w & 1) * 64;
    int r = lane & 15, g = lane >> 4;
    const unsigned short* Ag = Fb + (size_t)(nt * 128) * NL;
    bf16x8_t av[4][4];  // [kk][aa]
#pragma unroll
    for (int kk = 0; kk < 4; ++kk) {
        int c16 = kk * 4 + g;
#pragma unroll
        for (int aa = 0; aa < 4; ++aa)
            av[kk][aa] = *(const bf16x8_t*)(Ag + (size_t)(wn + aa * 16 + r) * NL + c16 * 8);
    }
    f32x4_t acc[4][4];
#pragma unroll
    for (int aa = 0; aa < 4; ++aa)
#pragma unroll
        for (int bb = 0; bb < 4; ++bb) acc[aa][bb] = (f32x4_t){0.f, 0.f, 0.f, 0.f};
#pragma unroll
    for (int kk = 0; kk < 4; ++kk) {
        int c16 = kk * 4 + g;
        bf16x8_t bv[4];
#pragma unroll
        for (int bb = 0; bb < 4; ++bb) {
            int rowB = wm + bb * 16 + r;
            bv[bb] = *(const bf16x8_t*)(lB + rowB * 256 + ((c16 * 16) ^ ((rowB & 7) << 4)));
        }
#pragma unroll
        for (int aa = 0; aa < 4; ++aa)
#pragma unroll
            for (int bb = 0; bb < 4; ++bb)
                acc[aa][bb] = __builtin_amdgcn_mfma_f32_16x16x32_bf16(bv[bb], av[kk][aa], acc[aa][bb], 0, 0, 0);
    }
#pragma unroll
    for (int aa = 0; aa < 4; ++aa) {
        int n = nt * 128 + wn + aa * 16 + r;
#pragma unroll
        for (int bb = 0; bb < 4; ++bb) {
            int m0 = wm + bb * 16 + g * 4;
            ushort4 o;
            o.x = f2bf(acc[aa][bb][0]); o.y = f2bf(acc[aa][bb][1]);
            o.z = f2bf(acc[aa][bb][2]); o.w = f2bf(acc[aa][bb][3]);
            *(ushort4*)&H[((size_t)n * 16 + a) * NL + m0] = o;
        }
    }
}

// ---------------- one preamble phase per launch (R10 structure) -------------
__global__ __launch_bounds__(256) void k_phase(int ph,
                                               const float* __restrict__ x,
                                               const float* __restrict__ tf,
                                               const float* __restrict__ tr,
                                               float* __restrict__ W,
                                               unsigned short* __restrict__ Wb,
                                               unsigned short* __restrict__ Fb,
                                               float* __restrict__ Cf,
                                               unsigned short* __restrict__ Cc,
                                               unsigned short* __restrict__ H) {
    __shared__ __align__(16) char lds[51200];
    int blk = blockIdx.x, t = threadIdx.x;
    if (ph == 0) {
        if (blk < 128) {
            float* xr = (float*)lds;  // [2][1024]
            int b0 = blk * 2;
            for (int idx = t; idx < 512; idx += 256) {
                int rr = idx >> 8, c = idx & 255;
                ((float4*)xr)[rr * 256 + c] =
                    ((const float4*)(x + (size_t)(b0 + rr) * NIN))[c];
            }
            __syncthreads();
            int rr = t >> 7, col = t & 127;
            const float* xp = xr + rr * NIN;
            float a = 0.f;
#pragma unroll 8
            for (int i = 0; i < NIN; ++i) a += xp[i] * tf[i * NL + col];
            Cf[(size_t)(b0 + rr) * NL + col] = a;
            Cc[(size_t)(b0 + rr) * NL + col] = f2bf(a);
        } else if (blk < 192) {
            int id = (blk - 128) * 256 + t;  // 0..16383
            float v = tr[id];
            W[id] = v;
            Wb[id] = f2bf(v);
            for (int i = id; i < NIN * NL; i += 16384) Fb[i] = f2bf(tf[i]);
        } else {
            int tt = blk - 192;  // T^2 = tr @ tr -> slot 1
            pmm32x64(tr, tr, W + MS, Wb + MS,
                     ((tt >> 1) & 3) * 32, (tt & 1) * 64, lds);
        }
    } else if (ph <= 3) {
        int m = 2 << (ph - 1);  // 2,4,8
        int i = blk >> 3, tt = blk & 7;
        pmm32x64(W + (size_t)i * MS, W + (size_t)(m - 1) * MS,
                 W + (size_t)(m + i) * MS, Wb + (size_t)(m + i) * MS,
                 ((tt >> 1) & 3) * 32, (tt & 1) * 64, lds);
    } else {
        int lv = ph - 4;    // 0..3
        int b2s = 15 + lv;  // W slot of T^{16<<lv}
        int ncp = 1 << lv;
        if (lv < 3 && blk < 8) {
            pmm32x64(W + (size_t)b2s * MS, W + (size_t)b2s * MS,
                     W + (size_t)(16 + lv) * MS, nullptr,
                     ((blk >> 1) & 3) * 32, (blk & 1) * 64, lds);
        } else if (blk >= 8 && blk < 8 + ncp * 16) {
            int rel = blk - 8, q = rel >> 4, tt = rel & 15;
            pmm32x64(Cf + (size_t)q * CMS, W + (size_t)b2s * MS,
                     Cf + (size_t)(ncp + q) * CMS, Cc + (size_t)(ncp + q) * CMS,
                     (tt >> 1) * 32, (tt & 1) * 64, lds);
        } else if (lv == 0 && blk >= 24 && blk < 152) {
            int rel = blk - 24;
            hmfma(Fb, Wb + (size_t)(rel >> 3) * MS, H, rel >> 3, rel & 7, lds);
        }
    }
}

// ---------------- k_main: out = Cc_j @ H^T -----------------------------------
// Register-accumulate 8 j per mf-stripe, wave-private LDS bounce, then NT
// stores of 2x512B CONTIGUOUS runs per instruction (vs 16x64B scattered).
__global__ __launch_bounds__(256, 2) void k_main(const unsigned short* __restrict__ Cc,
                                                 const unsigned short* __restrict__ H,
                                                 float* __restrict__ out) {
    int bid = blockIdx.x;
    int e = ((bid & 7) << 6) | (bid >> 3);  // XCD gets contiguous span
    int ct = e >> 2, bt = (e >> 1) & 1, jh = e & 1;
    __shared__ __align__(16) char lds[65536];
    char* lB = lds;  // 32 KB swizzled H tile
    int t = threadIdx.x;
    const unsigned short* Bg = H + (size_t)(ct * 128) * NL;
    for (int i = t; i < 2048; i += 256) {
        int row = i >> 4, c = i & 15;
        int sw = (c * 16) ^ ((row & 7) << 4);
        *(bf16x8_t*)(lB + row * 256 + sw) =
            *(const bf16x8_t*)(Bg + (size_t)row * NL + c * 8);
    }
    __syncthreads();
    int w = t >> 6, lane = t & 63;
    int wr = (w >> 1) * 64;   // wave b-row offset
    int wc = (w & 1) * 64;    // wave col offset
    int r = lane & 15, g = lane >> 4;

    // preload bv (H fragments) once
    bf16x8_t bv[4][4];  // [kk][nf]
#pragma unroll
    for (int kk = 0; kk < 4; ++kk) {
        int c16 = kk * 4 + g;
#pragma unroll
        for (int nf = 0; nf < 4; ++nf) {
            int rowB = wc + nf * 16 + r;
            bv[kk][nf] = *(const bf16x8_t*)(lB + rowB * 256 + ((c16 * 16) ^ ((rowB & 7) << 4)));
        }
    }

    char* slab = lds + 32768 + w * 8192;  // wave-private 8 KB bounce buffer

    for (int mf = 0; mf < 4; ++mf) {
        int brow_base = bt * 128 + wr + mf * 16;
        f32x4_t acc[8][4];  // [jj][nf]
#pragma unroll
        for (int jj = 0; jj < 8; ++jj)
#pragma unroll
            for (int nf = 0; nf < 4; ++nf) acc[jj][nf] = (f32x4_t){0.f, 0.f, 0.f, 0.f};
#pragma unroll
        for (int jj = 0; jj < 8; ++jj) {
            int j = jh * 8 + jj;
            const unsigned short* Arow =
                Cc + (size_t)j * CMS + (size_t)(brow_base + r) * NL;
            bf16x8_t av[4];
#pragma unroll
            for (int kk = 0; kk < 4; ++kk)
                av[kk] = *(const bf16x8_t*)(Arow + (kk * 4 + g) * 8);
#pragma unroll
            for (int kk = 0; kk < 4; ++kk)
#pragma unroll
                for (int nf = 0; nf < 4; ++nf)
                    acc[jj][nf] = __builtin_amdgcn_mfma_f32_16x16x32_bf16(
                        bv[kk][nf], av[kk], acc[jj][nf], 0, 0, 0);
        }
        // epilogue: per nf, bounce through wave-private slab -> contiguous NT
#pragma unroll
        for (int nf = 0; nf < 4; ++nf) {
            int nn = (w & 1) * 4 + nf;
            // write: lane (r,g) puts acc[jj][nf] (s = jj*16+g*4..+3) at
            // slab[r][s], XOR-swizzled to spread banks
#pragma unroll
            for (int jj = 0; jj < 8; ++jj) {
                int boff = (r * 512 + jj * 64 + g * 16) ^ ((r & 7) << 4);
                *(f32x4_t*)(slab + boff) = acc[jj][nf];
            }
            // read back linear [r][s] (conflict-free) + NT store 2x512B runs
#pragma unroll
            for (int i2 = 0; i2 < 8; ++i2) {
                int lin = i2 * 1024 + lane * 16;
                int rs = lin >> 9;
                f32x4_t v = *(const f32x4_t*)(slab + (lin ^ ((rs & 7) << 4)));
                size_t o = (size_t)(brow_base + rs) * (NIN * 256) +
                           (size_t)(ct * 8 + nn) * 256 + jh * 128 + ((lin & 511) >> 2);
                __builtin_nontemporal_store(v, (f32x4_t*)&out[o]);
            }
        }
    }
}

extern "C" void kernel_launch(void* const* d_in, const int* in_sizes, int n_in,
                              void* d_out, int out_size, void* d_ws, size_t ws_size,
                              hipStream_t stream) {
    const float* x = (const float*)d_in[0];
    const float* tf = (const float*)d_in[1];
    const float* tr = (const float*)d_in[2];
    float* out = (float*)d_out;

    // workspace (~9 MB)
    float* W = (float*)d_ws;                              // 20 f32 slots
    float* Cf = W + (size_t)20 * MS;                      // 16 x [256][128] f32
    unsigned short* Wb = (unsigned short*)(Cf + (size_t)16 * CMS);  // 16 bf16 slots
    unsigned short* Fb = Wb + (size_t)16 * MS;            // [1024][128] bf16
    unsigned short* Cc = Fb + (size_t)NIN * NL;           // 16 x [256][128] bf16
    unsigned short* H = Cc + (size_t)16 * CMS;            // [16384][128] bf16 (4 MB)

    static const int grids[8] = {200, 16, 32, 64, 152, 40, 72, 136};
    for (int ph = 0; ph < 8; ++ph) {
        k_phase<<<grids[ph], 256, 0, stream>>>(ph, x, tf, tr, W, Wb, Fb,
                                               Cf, Cc, H);
    }
    k_main<<<512, 256, 0, stream>>>(Cc, H, out);
}

// Round 15
// 156.303 us; speedup vs baseline: 1.7480x; 1.0134x over previous
//
#include <hip/hip_runtime.h>
#include <hip/hip_bf16.h>

#define NIN 1024
#define NL 128
#define MS 16384    // 128x128 matrix slot (elements)
#define CMS 32768   // 256x128 C slot (elements)

typedef __attribute__((ext_vector_type(8))) short bf16x8_t;
typedef __attribute__((ext_vector_type(4))) float f32x4_t;

__device__ inline unsigned short f2bf(float f) {
    __hip_bfloat16 h = __float2bfloat16(f);
    return *reinterpret_cast<unsigned short*>(&h);
}

// f32 tile: D[r0..r0+32)[j0..j0+64) = A_rows @ B(128x128); optional bf16 copy.
__device__ __forceinline__ void pmm32x64(const float* __restrict__ A,
                                         const float* __restrict__ B,
                                         float* __restrict__ D,
                                         unsigned short* __restrict__ Db,
                                         int r0, int j0, char* lds) {
    float* Bl = (float*)lds;                        // [128][64] 32 KB
    float (*At)[36] = (float(*)[36])(lds + 32768);  // [128][36] 18 KB
    int t = threadIdx.x;
    for (int idx = t; idx < 2048; idx += 256) {
        int row = idx >> 4, c = idx & 15;
        *(float4*)&Bl[row * 64 + c * 4] = *(const float4*)&B[row * NL + j0 + c * 4];
    }
    for (int idx = t; idx < 4096; idx += 256) {
        int m = idx >> 7, kk = idx & 127;
        At[kk][m] = A[(size_t)(r0 + m) * NL + kk];
    }
    __syncthreads();
    int j = t & 63, rg = t >> 6;
    float acc[8];
#pragma unroll
    for (int q = 0; q < 8; ++q) acc[q] = 0.f;
#pragma unroll 4
    for (int kk = 0; kk < NL; ++kk) {
        float bv = Bl[kk * 64 + j];
        const f32x4_t* ap = (const f32x4_t*)&At[kk][rg * 8];
        f32x4_t a0 = ap[0], a1 = ap[1];
        acc[0] += a0[0] * bv; acc[1] += a0[1] * bv;
        acc[2] += a0[2] * bv; acc[3] += a0[3] * bv;
        acc[4] += a1[0] * bv; acc[5] += a1[1] * bv;
        acc[6] += a1[2] * bv; acc[7] += a1[3] * bv;
    }
#pragma unroll
    for (int q = 0; q < 8; ++q) {
        size_t off = (size_t)(r0 + rg * 8 + q) * NL + j0 + j;
        D[off] = acc[q];
        if (Db) Db[off] = f2bf(acc[q]);
    }
}

// H tile (bf16 MFMA, swapped operands): H[(n*16+a)][m] = sum_l F[n,l]*T^{a+1}[m,l]
__device__ __forceinline__ void hmfma(const unsigned short* __restrict__ Fb,
                                      const unsigned short* __restrict__ Wa,
                                      unsigned short* __restrict__ H,
                                      int a, int nt, char* lds) {
    char* lB = lds;  // swizzled T tile, 32 KB
    int t = threadIdx.x;
    for (int i = t; i < 2048; i += 256) {
        int row = i >> 4, c = i & 15;
        int sw = (c * 16) ^ ((row & 7) << 4);
        *(bf16x8_t*)(lB + row * 256 + sw) = *(const bf16x8_t*)(Wa + (size_t)row * NL + c * 8);
    }
    __syncthreads();
    int w = t >> 6, lane = t & 63;
    int wn = (w >> 1) * 64, wm = (w & 1) * 64;
    int r = lane & 15, g = lane >> 4;
    const unsigned short* Ag = Fb + (size_t)(nt * 128) * NL;
    bf16x8_t av[4][4];  // [kk][aa]
#pragma unroll
    for (int kk = 0; kk < 4; ++kk) {
        int c16 = kk * 4 + g;
#pragma unroll
        for (int aa = 0; aa < 4; ++aa)
            av[kk][aa] = *(const bf16x8_t*)(Ag + (size_t)(wn + aa * 16 + r) * NL + c16 * 8);
    }
    f32x4_t acc[4][4];
#pragma unroll
    for (int aa = 0; aa < 4; ++aa)
#pragma unroll
        for (int bb = 0; bb < 4; ++bb) acc[aa][bb] = (f32x4_t){0.f, 0.f, 0.f, 0.f};
#pragma unroll
    for (int kk = 0; kk < 4; ++kk) {
        int c16 = kk * 4 + g;
        bf16x8_t bv[4];
#pragma unroll
        for (int bb = 0; bb < 4; ++bb) {
            int rowB = wm + bb * 16 + r;
            bv[bb] = *(const bf16x8_t*)(lB + rowB * 256 + ((c16 * 16) ^ ((rowB & 7) << 4)));
        }
#pragma unroll
        for (int aa = 0; aa < 4; ++aa)
#pragma unroll
            for (int bb = 0; bb < 4; ++bb)
                acc[aa][bb] = __builtin_amdgcn_mfma_f32_16x16x32_bf16(bv[bb], av[kk][aa], acc[aa][bb], 0, 0, 0);
    }
#pragma unroll
    for (int aa = 0; aa < 4; ++aa) {
        int n = nt * 128 + wn + aa * 16 + r;
#pragma unroll
        for (int bb = 0; bb < 4; ++bb) {
            int m0 = wm + bb * 16 + g * 4;
            ushort4 o;
            o.x = f2bf(acc[aa][bb][0]); o.y = f2bf(acc[aa][bb][1]);
            o.z = f2bf(acc[aa][bb][2]); o.w = f2bf(acc[aa][bb][3]);
            *(ushort4*)&H[((size_t)n * 16 + a) * NL + m0] = o;
        }
    }
}

// ---------------- one preamble phase per launch (R10 structure) -------------
__global__ __launch_bounds__(256) void k_phase(int ph,
                                               const float* __restrict__ x,
                                               const float* __restrict__ tf,
                                               const float* __restrict__ tr,
                                               float* __restrict__ W,
                                               unsigned short* __restrict__ Wb,
                                               unsigned short* __restrict__ Fb,
                                               float* __restrict__ Cf,
                                               unsigned short* __restrict__ Cc,
                                               unsigned short* __restrict__ H) {
    __shared__ __align__(16) char lds[51200];
    int blk = blockIdx.x, t = threadIdx.x;
    if (ph == 0) {
        if (blk < 128) {
            float* xr = (float*)lds;  // [2][1024]
            int b0 = blk * 2;
            for (int idx = t; idx < 512; idx += 256) {
                int rr = idx >> 8, c = idx & 255;
                ((float4*)xr)[rr * 256 + c] =
                    ((const float4*)(x + (size_t)(b0 + rr) * NIN))[c];
            }
            __syncthreads();
            int rr = t >> 7, col = t & 127;
            const float* xp = xr + rr * NIN;
            float a = 0.f;
#pragma unroll 8
            for (int i = 0; i < NIN; ++i) a += xp[i] * tf[i * NL + col];
            Cf[(size_t)(b0 + rr) * NL + col] = a;
            Cc[(size_t)(b0 + rr) * NL + col] = f2bf(a);
        } else if (blk < 192) {
            int id = (blk - 128) * 256 + t;  // 0..16383
            float v = tr[id];
            W[id] = v;
            Wb[id] = f2bf(v);
            for (int i = id; i < NIN * NL; i += 16384) Fb[i] = f2bf(tf[i]);
        } else {
            int tt = blk - 192;  // T^2 = tr @ tr -> slot 1
            pmm32x64(tr, tr, W + MS, Wb + MS,
                     ((tt >> 1) & 3) * 32, (tt & 1) * 64, lds);
        }
    } else if (ph <= 3) {
        int m = 2 << (ph - 1);  // 2,4,8
        int i = blk >> 3, tt = blk & 7;
        pmm32x64(W + (size_t)i * MS, W + (size_t)(m - 1) * MS,
                 W + (size_t)(m + i) * MS, Wb + (size_t)(m + i) * MS,
                 ((tt >> 1) & 3) * 32, (tt & 1) * 64, lds);
    } else {
        int lv = ph - 4;    // 0..3
        int b2s = 15 + lv;  // W slot of T^{16<<lv}
        int ncp = 1 << lv;
        if (lv < 3 && blk < 8) {
            pmm32x64(W + (size_t)b2s * MS, W + (size_t)b2s * MS,
                     W + (size_t)(16 + lv) * MS, nullptr,
                     ((blk >> 1) & 3) * 32, (blk & 1) * 64, lds);
        } else if (blk >= 8 && blk < 8 + ncp * 16) {
            int rel = blk - 8, q = rel >> 4, tt = rel & 15;
            pmm32x64(Cf + (size_t)q * CMS, W + (size_t)b2s * MS,
                     Cf + (size_t)(ncp + q) * CMS, Cc + (size_t)(ncp + q) * CMS,
                     (tt >> 1) * 32, (tt & 1) * 64, lds);
        } else if (lv == 0 && blk >= 24 && blk < 152) {
            int rel = blk - 24;
            hmfma(Fb, Wb + (size_t)(rel >> 3) * MS, H, rel >> 3, rel & 7, lds);
        }
    }
}

// ---------------- k_main: out = Cc_j @ H^T ----------------------------------
// nf-outer (low VGPR), 4KB/wave rotation-swizzled bounce slab, LDS 48KB ->
// 3 blocks/CU (12 waves), NORMAL stores (L2 line assembly; no NT).
__global__ __launch_bounds__(256) void k_main(const unsigned short* __restrict__ Cc,
                                              const unsigned short* __restrict__ H,
                                              float* __restrict__ out) {
    int bid = blockIdx.x;
    int e = ((bid & 7) << 6) | (bid >> 3);  // XCD gets contiguous span
    int ct = e >> 2, bt = (e >> 1) & 1, jh = e & 1;
    __shared__ __align__(16) char lds[49152];
    char* lB = lds;  // 32 KB swizzled H tile
    int t = threadIdx.x;
    const unsigned short* Bg = H + (size_t)(ct * 128) * NL;
    for (int i = t; i < 2048; i += 256) {
        int row = i >> 4, c = i & 15;
        int sw = (c * 16) ^ ((row & 7) << 4);
        *(bf16x8_t*)(lB + row * 256 + sw) =
            *(const bf16x8_t*)(Bg + (size_t)row * NL + c * 8);
    }
    __syncthreads();
    int w = t >> 6, lane = t & 63;
    int wr = (w >> 1) * 64;   // wave b-row offset
    int wc = (w & 1) * 64;    // wave col offset
    int r = lane & 15, g = lane >> 4;
    char* slab = lds + 32768 + w * 4096;  // wave-private 4 KB bounce

    for (int mf = 0; mf < 4; ++mf) {
        int brow_base = bt * 128 + wr + mf * 16;
#pragma unroll
        for (int g0 = 0; g0 < 2; ++g0) {
            for (int nf = 0; nf < 4; ++nf) {
                int nn = (w & 1) * 4 + nf;
                int rowB = wc + nf * 16 + r;
                f32x4_t acc4[4];
#pragma unroll
                for (int q = 0; q < 4; ++q) acc4[q] = (f32x4_t){0.f, 0.f, 0.f, 0.f};
#pragma unroll
                for (int jj4 = 0; jj4 < 4; ++jj4) {
                    int j = jh * 8 + g0 * 4 + jj4;
                    const unsigned short* Arow =
                        Cc + (size_t)j * CMS + (size_t)(brow_base + r) * NL;
#pragma unroll
                    for (int kk = 0; kk < 4; ++kk) {
                        bf16x8_t av = *(const bf16x8_t*)(Arow + (kk * 4 + g) * 8);
                        bf16x8_t bvv = *(const bf16x8_t*)(
                            lB + rowB * 256 + (((kk * 4 + g) * 16) ^ ((rowB & 7) << 4)));
                        acc4[jj4] = __builtin_amdgcn_mfma_f32_16x16x32_bf16(
                            bvv, av, acc4[jj4], 0, 0, 0);
                    }
                }
                // bounce: slab[r][col], col rotated by r*32B (2-way banks, free)
#pragma unroll
                for (int jj4 = 0; jj4 < 4; ++jj4) {
                    int boff = r * 256 + ((jj4 * 64 + g * 16 + r * 32) & 255);
                    *(f32x4_t*)(slab + boff) = acc4[jj4];
                }
                // read back + contiguous normal stores (4 x 256B runs / instr)
#pragma unroll
                for (int i2 = 0; i2 < 4; ++i2) {
                    int lin = i2 * 1024 + lane * 16;
                    int rs = lin >> 8, cb = lin & 255;
                    f32x4_t v = *(const f32x4_t*)(slab + rs * 256 + ((cb + rs * 32) & 255));
                    size_t o = (size_t)(brow_base + rs) * (NIN * 256) +
                               (size_t)(ct * 8 + nn) * 256 + jh * 128 + g0 * 64 + (cb >> 2);
                    *(f32x4_t*)&out[o] = v;
                }
            }
        }
    }
}

extern "C" void kernel_launch(void* const* d_in, const int* in_sizes, int n_in,
                              void* d_out, int out_size, void* d_ws, size_t ws_size,
                              hipStream_t stream) {
    const float* x = (const float*)d_in[0];
    const float* tf = (const float*)d_in[1];
    const float* tr = (const float*)d_in[2];
    float* out = (float*)d_out;

    // workspace (~9 MB)
    float* W = (float*)d_ws;                              // 20 f32 slots
    float* Cf = W + (size_t)20 * MS;                      // 16 x [256][128] f32
    unsigned short* Wb = (unsigned short*)(Cf + (size_t)16 * CMS);  // 16 bf16 slots
    unsigned short* Fb = Wb + (size_t)16 * MS;            // [1024][128] bf16
    unsigned short* Cc = Fb + (size_t)NIN * NL;           // 16 x [256][128] bf16
    unsigned short* H = Cc + (size_t)16 * CMS;            // [16384][128] bf16 (4 MB)

    static const int grids[8] = {200, 16, 32, 64, 152, 40, 72, 136};
    for (int ph = 0; ph < 8; ++ph) {
        k_phase<<<grids[ph], 256, 0, stream>>>(ph, x, tf, tr, W, Wb, Fb,
                                               Cf, Cc, H);
    }
    k_main<<<512, 256, 0, stream>>>(Cc, H, out);
}